// Round 13
// baseline (128.666 us; speedup 1.0000x reference)
//
#include <hip/hip_runtime.h>
#include <math.h>

// Problem constants (hardcoded in the reference layer)
#define B_ROWS 32768
#define DIM    1024
#define NC     7
#define D4     (DIM/4)
#define RPB    64          // rows per block
#define GRP    32          // rows per 256-thread group (2 groups)
#define BLK    512
#define NBLK   (B_ROWS / RPB)   // 512 blocks

#define ALPHA_C   0.5f
#define LAMBDA2_C 0.5f

// ws layout (floats):
//  [64..7231]   featsum[7*1024]
//  [7232..7238] counts[7]
//  [7239]       done-counter (unsigned)
#define WS_FSUM   64
#define WS_CNT    (64 + NC*DIM)
#define WS_DONE   (WS_CNT + NC)
#define WS_TOTAL  (WS_DONE + 1)

// triangular index for pair (j,m), j<=m, 28 entries
__device__ __forceinline__ int triIdx(int j, int m) {
    return j * 7 - (j * (j - 1)) / 2 + (m - j);
}

// Full wave64 sum via DPP (VALU-only, no DS pipe). Result valid in lane 63.
__device__ __forceinline__ float waveSum64_dpp(float v) {
#define DPP_ADD(CTRL)                                                        \
    v += __int_as_float(__builtin_amdgcn_update_dpp(                         \
        0, __float_as_int(v), CTRL, 0xF, 0xF, false))
    DPP_ADD(0x111);  // row_shr:1
    DPP_ADD(0x112);  // row_shr:2
    DPP_ADD(0x114);  // row_shr:4
    DPP_ADD(0x118);  // row_shr:8  -> lane15 of each row16 has row sum
    DPP_ADD(0x142);  // row_bcast15 -> lane31 = rows0+1, lane63 = rows2+3
    DPP_ADD(0x143);  // row_bcast31 -> lane63 = all 64 lanes
#undef DPP_ADD
    return v;
}

// ---------------------------------------------------------------------------
// Single main kernel (normal launch), 512 blocks x 512 threads.
//  - in-block redundant 7x7 Gram from staged cen (4 pairs/wave, DPP) -> smallG
//  - EXACT round-5 hot loop (select-FMA register acc, 8-row batches, DPP)
//  - pd derived from smallG inside the result-write branch
//  - featsum flush: coalesced 4B atomics into memset-zeroed ws
//  - last-block pattern replaces the finish kernel: done-counter + agent-scope
//    atomic loads of featsum/counts (cross-XCD safe), coefs from own smallG
// ---------------------------------------------------------------------------
__global__ __launch_bounds__(BLK, 4)
void main_kernel(const float4* __restrict__ feats4,
                 const float*  __restrict__ labels,
                 const float4* __restrict__ centers4,
                 float* __restrict__ ws,
                 float* __restrict__ result,
                 float4* __restrict__ outC) {
    __shared__ __align__(16) float cen[NC * DIM];   // 28 KB (reused for flush)
    __shared__ float partial[RPB * 4];              // 1 KB
    __shared__ int   lbls[RPB];
    __shared__ float smallG[28];                    // triangular Gram
    __shared__ bool  amLast;

    const int tid  = threadIdx.x;
    const int g    = tid >> 8;          // row-group (0/1)
    const int ct   = tid & 255;         // column-thread within group
    const int lane = tid & 63;
    const int wid  = tid >> 6;          // wave in block (0..7)
    const int wgrp = wid & 3;           // wave within 256-thread group
    const int row0 = blockIdx.x * RPB;

    float* featsum = ws + WS_FSUM;
    float* counts  = ws + WS_CNT;

    // stage centers into LDS
    for (int i = tid; i < NC * D4; i += BLK) ((float4*)cen)[i] = centers4[i];

    // decode one-hot labels for this block's rows
    if (tid < RPB) {
        const float* lr = labels + (size_t)(row0 + tid) * NC;
        int l = 0;
#pragma unroll
        for (int j = 1; j < NC; ++j) l = (lr[j] > 0.5f) ? j : l;
        lbls[tid] = l;
    }
    __syncthreads();

    // in-block Gram: wave wid computes pairs wid*4 .. wid*4+3 (p < 28)
#pragma unroll
    for (int k = 0; k < 4; ++k) {
        const int p = wid * 4 + k;
        if (p < 28) {
            int j = 0, q = p;
            while (q >= 7 - j) { q -= 7 - j; ++j; }
            const int m = j + q;
            float s = 0.0f;
#pragma unroll
            for (int c4 = 0; c4 < 4; ++c4) {
                const float4 a = ((const float4*)cen)[j * D4 + lane + c4 * 64];
                const float4 b = ((const float4*)cen)[m * D4 + lane + c4 * 64];
                s += a.x * b.x + a.y * b.y + a.z * b.z + a.w * b.w;
            }
            s = waveSum64_dpp(s);
            if (lane == 63) smallG[p] = s;
        }
    }
    // (no syncthreads needed here: smallG is read only after the post-loop one)

    // per-class row counts (threads 0..6, registers)
    float mycnt = 0.0f;
    if (tid < NC) {
        for (int r = 0; r < RPB; ++r) mycnt += (lbls[r] == tid) ? 1.0f : 0.0f;
    }

    // ---- hot loop: EXACT round-5 body ----
    float4 acc[NC];
#pragma unroll
    for (int c = 0; c < NC; ++c) acc[c] = make_float4(0.f, 0.f, 0.f, 0.f);

    const float4* fp = feats4 + (size_t)(row0 + g * GRP) * D4 + ct;

#pragma unroll 1
    for (int ch = 0; ch < GRP / 8; ++ch) {
        const int rb = ch * 8;
        // batched loads: 8 outstanding 16B loads
        float4 x[8];
#pragma unroll
        for (int r = 0; r < 8; ++r) x[r] = fp[(rb + r) * D4];

#pragma unroll
        for (int r = 0; r < 8; ++r) {
            const int lbl = __builtin_amdgcn_readfirstlane(lbls[g * GRP + rb + r]);
            const float4 c4 = *(const float4*)&cen[lbl * DIM + ct * 4];
            const float dx = x[r].x - c4.x, dy = x[r].y - c4.y;
            const float dz = x[r].z - c4.z, dw = x[r].w - c4.w;
            float ssq = fmaf(dx, dx, fmaf(dy, dy, fmaf(dz, dz, dw * dw)));
#pragma unroll
            for (int c = 0; c < NC; ++c) {
                const float kc = (lbl == c) ? 1.0f : 0.0f;   // SALU compare
                acc[c].x = fmaf(kc, x[r].x, acc[c].x);
                acc[c].y = fmaf(kc, x[r].y, acc[c].y);
                acc[c].z = fmaf(kc, x[r].z, acc[c].z);
                acc[c].w = fmaf(kc, x[r].w, acc[c].w);
            }
            ssq = waveSum64_dpp(ssq);                // VALU-only reduce
            if (lane == 63) partial[(g * GRP + rb + r) * 4 + wgrp] = ssq;
        }
    }
    __syncthreads();   // partial + smallG ready

    // finish per-row loss (pd derived from smallG, divergent branch only)
    if (tid < RPB) {
        float inv[NC];
#pragma unroll
        for (int j = 0; j < NC; ++j)
            inv[j] = 1.0f / sqrtf(smallG[triIdx(j, j)]);
        float pdsum = 0.0f;
#pragma unroll
        for (int j = 0; j < NC; ++j)
#pragma unroll
            for (int m = j + 1; m < NC; ++m)
                pdsum += 2.0f * fmaf(smallG[triIdx(j, m)], inv[j] * inv[m], 1.0f);
        const float pd = LAMBDA2_C * pdsum;

        const float s = partial[tid * 4] + partial[tid * 4 + 1] +
                        partial[tid * 4 + 2] + partial[tid * 4 + 3];
        result[row0 + tid] = 0.5f * s + pd;
    }

    // combine both groups' register accs in (dead) cen LDS, then one flush
    if (g == 0) {
#pragma unroll
        for (int c = 0; c < NC; ++c)
            *(float4*)&cen[c * DIM + ct * 4] = acc[c];
    }
    __syncthreads();
    if (g == 1) {
#pragma unroll
        for (int c = 0; c < NC; ++c) {
            float4 t = *(const float4*)&cen[c * DIM + ct * 4];
            t.x += acc[c].x; t.y += acc[c].y; t.z += acc[c].z; t.w += acc[c].w;
            *(float4*)&cen[c * DIM + ct * 4] = t;
        }
    }
    __syncthreads();

    // lane-consecutive 4B atomics (coalesced at L2/IF)
    for (int i = tid; i < NC * DIM; i += BLK) unsafeAtomicAdd(&featsum[i], cen[i]);
    if (tid < NC) unsafeAtomicAdd(&counts[tid], mycnt);

    // ---- last-block epilogue (replaces finish kernel) ----
    __threadfence();   // per-thread: flush atomics to device scope
    __syncthreads();
    if (tid == 0) {
        unsigned old = __hip_atomic_fetch_add((unsigned*)&ws[WS_DONE], 1u,
                                              __ATOMIC_ACQ_REL,
                                              __HIP_MEMORY_SCOPE_AGENT);
        amLast = (old == NBLK - 1);
    }
    __syncthreads();

    if (amLast) {
        __threadfence();
        // coefs from own smallG (still in LDS)
        float inv[NC], sumInv = 0.0f;
#pragma unroll
        for (int j = 0; j < NC; ++j) {
            inv[j] = 1.0f / sqrtf(smallG[triIdx(j, j)]);
            sumInv += inv[j];
        }
        const float KADD = LAMBDA2_C / (float)(NC - 1);

        for (int i = tid; i < NC * 256; i += BLK) {
            const int c = i >> 8;
            const int t = i & 255;

            const float cnt = __hip_atomic_load(&counts[c], __ATOMIC_RELAXED,
                                                __HIP_MEMORY_SCOPE_AGENT);
            const float coef1  = inv[c] * (sumInv - inv[c]);
            const float rdenom = 1.0f / (cnt + 1.0f);

            const float* fsp = &featsum[c * DIM + t * 4];
            float4 fs;
            fs.x = __hip_atomic_load(fsp + 0, __ATOMIC_RELAXED, __HIP_MEMORY_SCOPE_AGENT);
            fs.y = __hip_atomic_load(fsp + 1, __ATOMIC_RELAXED, __HIP_MEMORY_SCOPE_AGENT);
            fs.z = __hip_atomic_load(fsp + 2, __ATOMIC_RELAXED, __HIP_MEMORY_SCOPE_AGENT);
            fs.w = __hip_atomic_load(fsp + 3, __ATOMIC_RELAXED, __HIP_MEMORY_SCOPE_AGENT);

            const float4 cv = centers4[c * D4 + t];
            float Tx = cv.x * coef1, Ty = cv.y * coef1,
                  Tz = cv.z * coef1, Tw = cv.w * coef1;
#pragma unroll
            for (int m = 0; m < NC; ++m) {
                if (m == c) continue;
                const float gcm = smallG[triIdx(min(c, m), max(c, m))];
                const float k2  = gcm * inv[c] * inv[m] * inv[m] * inv[m];
                const float4 cm = centers4[m * D4 + t];
                Tx -= k2 * cm.x; Ty -= k2 * cm.y; Tz -= k2 * cm.z; Tw -= k2 * cm.w;
            }

            float4 o;
            o.x = cv.x - ALPHA_C * ((cnt * cv.x - fs.x) * rdenom) + KADD * Tx;
            o.y = cv.y - ALPHA_C * ((cnt * cv.y - fs.y) * rdenom) + KADD * Ty;
            o.z = cv.z - ALPHA_C * ((cnt * cv.z - fs.z) * rdenom) + KADD * Tz;
            o.w = cv.w - ALPHA_C * ((cnt * cv.w - fs.w) * rdenom) + KADD * Tw;
            outC[c * D4 + t] = o;
        }
    }
}

// ---------------------------------------------------------------------------
extern "C" void kernel_launch(void* const* d_in, const int* in_sizes, int n_in,
                              void* d_out, int out_size, void* d_ws, size_t ws_size,
                              hipStream_t stream) {
    const float4* feats4   = (const float4*)d_in[0];   // (32768, 1024)
    const float*  labels   = (const float*)d_in[1];    // (32768, 7) one-hot
    const float4* centers4 = (const float4*)d_in[2];   // (7, 1024)
    float* out = (float*)d_out;                        // [32768 result | 7168 new_centers]
    float* ws  = (float*)d_ws;

    // zero featsum + counts + done-counter (graph-capturable)
    hipMemsetAsync(d_ws, 0, (size_t)WS_TOTAL * sizeof(float), stream);

    main_kernel<<<NBLK, BLK, 0, stream>>>(
        feats4, labels, centers4, ws, out, (float4*)(out + B_ROWS));
}